// Round 4
// baseline (61.213 us; speedup 1.0000x reference)
//
#include <hip/hip_runtime.h>

// RoiPoolingConv: fm [64,64,1024] f32 NHWC, rois [300,4] int32 (x,y,w,h),
// out [300,14,14,1024] f32.
//
//  1. sort_items: counting-sort the 4200 (roi,py) work items by y0 into a
//     permutation in d_ws (single block).
//  2. roi_pool_row_kernel: one block per work item, 256 threads x float4 over
//     1024 channels, loop px. y0-sorted + bijective XCD swizzle -> per-XCD L2
//     read locality. NT stores keep the 241 MB output stream out of L2.
//     NEW: block-uniform register cache of the last two corner columns —
//     scalar (readfirstlane) indices so the column loads sit behind s_cbranch
//     and are skipped when the column is already in registers.

#define POOL 14
#define FMW 64
#define CH 1024
#define C4 (CH / 4)   // 256 float4 per pixel

typedef float f4 __attribute__((ext_vector_type(4)));

__global__ __launch_bounds__(1024) void sort_items_kernel(
    const int* __restrict__ rois, int num_items, int* __restrict__ perm)
{
    __shared__ int base[64];
    const int tid = threadIdx.x;

    if (tid < 64) base[tid] = 0;
    __syncthreads();

    for (int i = tid; i < num_items; i += blockDim.x) {
        const int roi = i / POOL, py = i % POOL;
        const int y = rois[roi * 4 + 1], h = rois[roi * 4 + 3];
        const float fy = (float)y + (float)py * ((float)h * (1.0f / 14.0f));
        const int y0 = (int)floorf(fy);
        atomicAdd(&base[y0 & 63], 1);
    }
    __syncthreads();

    if (tid == 0) {
        int s = 0;
        for (int k = 0; k < 64; ++k) { int c = base[k]; base[k] = s; s += c; }
    }
    __syncthreads();

    for (int i = tid; i < num_items; i += blockDim.x) {
        const int roi = i / POOL, py = i % POOL;
        const int y = rois[roi * 4 + 1], h = rois[roi * 4 + 3];
        const float fy = (float)y + (float)py * ((float)h * (1.0f / 14.0f));
        const int y0 = (int)floorf(fy);
        const int pos = atomicAdd(&base[y0 & 63], 1);
        perm[pos] = i;
    }
}

__global__ __launch_bounds__(256) void roi_pool_row_kernel(
    const float* __restrict__ fm,
    const int* __restrict__ rois,
    const int* __restrict__ perm,
    int nw,
    float* __restrict__ out)
{
    const int per = nw >> 3;
    const int b   = blockIdx.x;
    const int sb  = (b & 7) * per + (b >> 3);
    const int item = __builtin_amdgcn_readfirstlane(perm[sb]);

    const int py  = item % POOL;
    const int roi = item / POOL;

    const int4 r = *reinterpret_cast<const int4*>(rois + roi * 4);
    const int x = __builtin_amdgcn_readfirstlane(r.x);
    const int y = __builtin_amdgcn_readfirstlane(r.y);
    const int w = __builtin_amdgcn_readfirstlane(r.z);
    const int h = __builtin_amdgcn_readfirstlane(r.w);

    // Legacy-TF bilinear (align_corners=False, no half-pixel centers)
    const float fy = (float)y + (float)py * ((float)h * (1.0f / 14.0f));
    const int   y0 = __builtin_amdgcn_readfirstlane((int)floorf(fy));
    const int   y1 = min(y0 + 1, y + h - 1);
    const float wy = fy - (float)y0;

    const int c = threadIdx.x;  // float4 lane over channels
    const f4* row0 = reinterpret_cast<const f4*>(fm) + (size_t)y0 * FMW * C4 + c;
    const f4* row1 = reinterpret_cast<const f4*>(fm) + (size_t)y1 * FMW * C4 + c;
    f4* op = reinterpret_cast<f4*>(out) + ((size_t)roi * POOL + py) * POOL * C4 + c;

    const float wscale = (float)w * (1.0f / 14.0f);
    const int   xmax   = x + w - 1;

    // register cache: columns cx0 (tl,bl) and cx1 (tr,br)
    int cx0 = -1, cx1 = -1;
    f4 tl, bl, tr, br;

    for (int px = 0; px < POOL; ++px) {
        const float fx = (float)x + (float)px * wscale;
        const int   x0 = __builtin_amdgcn_readfirstlane((int)floorf(fx));
        const int   x1 = min(x0 + 1, xmax);
        const float wx = fx - (float)x0;

        f4 ntl, nbl, ntr, nbr;
        if (x0 == cx0)      { ntl = tl; nbl = bl; }
        else if (x0 == cx1) { ntl = tr; nbl = br; }
        else                { ntl = row0[(size_t)x0 * C4]; nbl = row1[(size_t)x0 * C4]; }

        if (x1 == x0)       { ntr = ntl; nbr = nbl; }
        else if (x1 == cx1) { ntr = tr; nbr = br; }
        else                { ntr = row0[(size_t)x1 * C4]; nbr = row1[(size_t)x1 * C4]; }

        tl = ntl; bl = nbl; tr = ntr; br = nbr;
        cx0 = x0; cx1 = x1;

        const f4 top = tl + wx * (tr - tl);
        const f4 bot = bl + wx * (br - bl);
        const f4 o   = top + wy * (bot - top);

        __builtin_nontemporal_store(o, op + (size_t)px * C4);
    }
}

// Fallback without permutation (if ws is too small): identity order.
__global__ __launch_bounds__(256) void roi_pool_row_kernel_noperm(
    const float* __restrict__ fm,
    const int* __restrict__ rois,
    int nw,
    float* __restrict__ out)
{
    const int b = blockIdx.x;

    const int py  = b % POOL;
    const int roi = b / POOL;

    const int4 r = *reinterpret_cast<const int4*>(rois + roi * 4);
    const int x = r.x, y = r.y, w = r.z, h = r.w;

    const float fy = (float)y + (float)py * ((float)h * (1.0f / 14.0f));
    const int   y0 = (int)floorf(fy);
    const int   y1 = min(y0 + 1, y + h - 1);
    const float wy = fy - (float)y0;

    const int c = threadIdx.x;
    const f4* row0 = reinterpret_cast<const f4*>(fm) + (size_t)y0 * FMW * C4 + c;
    const f4* row1 = reinterpret_cast<const f4*>(fm) + (size_t)y1 * FMW * C4 + c;
    f4* op = reinterpret_cast<f4*>(out) + ((size_t)roi * POOL + py) * POOL * C4 + c;

    const float wscale = (float)w * (1.0f / 14.0f);

    for (int px = 0; px < POOL; ++px) {
        const float fx = (float)x + (float)px * wscale;
        const int   x0 = (int)floorf(fx);
        const int   x1 = min(x0 + 1, x + w - 1);
        const float wx = fx - (float)x0;

        const f4 tl = row0[(size_t)x0 * C4];
        const f4 tr = row0[(size_t)x1 * C4];
        const f4 bl = row1[(size_t)x0 * C4];
        const f4 br = row1[(size_t)x1 * C4];

        const f4 top = tl + wx * (tr - tl);
        const f4 bot = bl + wx * (br - bl);
        const f4 o   = top + wy * (bot - top);

        __builtin_nontemporal_store(o, op + (size_t)px * C4);
    }
}

extern "C" void kernel_launch(void* const* d_in, const int* in_sizes, int n_in,
                              void* d_out, int out_size, void* d_ws, size_t ws_size,
                              hipStream_t stream) {
    const float* fm  = (const float*)d_in[0];   // [1,64,64,1024] f32
    const int* rois  = (const int*)d_in[1];     // [1,300,4] i32
    float* out       = (float*)d_out;           // [1,300,14,14,1024] f32

    const int num_rois = in_sizes[1] / 4;       // 300
    const int nw = num_rois * POOL;             // 4200 work items

    if (ws_size >= (size_t)nw * sizeof(int) && (nw & 7) == 0) {
        int* perm = (int*)d_ws;
        sort_items_kernel<<<1, 1024, 0, stream>>>(rois, nw, perm);
        roi_pool_row_kernel<<<nw, 256, 0, stream>>>(fm, rois, perm, nw, out);
    } else {
        roi_pool_row_kernel_noperm<<<nw, 256, 0, stream>>>(fm, rois, nw, out);
    }
}

// Round 5
// 60.678 us; speedup vs baseline: 1.0088x; 1.0088x over previous
//
#include <hip/hip_runtime.h>

// RoiPoolingConv: fm [64,64,1024] f32 NHWC, rois [300,4] int32 (x,y,w,h),
// out [300,14,14,1024] f32.
//
//  1. sort_items: counting-sort 4200 (roi,py) items by y0 into perm (d_ws).
//     rois LDS-cached; 64-bin exclusive scan done wave-parallel (shfl_up).
//  2. roi_pool_row_kernel: one block per item, 256 threads x float4 over
//     1024 channels, loop px. y0-sorted + bijective XCD swizzle -> per-XCD
//     L2 read locality. NT stores keep the 241 MB output out of L2.
//     Software-pipelined px loop: next-px loads are issued BEFORE the
//     current-px store, so vmcnt waits for loads never force store drain.

#define POOL 14
#define FMW 64
#define CH 1024
#define C4 (CH / 4)        // 256 float4 per pixel
#define MAX_ITEMS (300 * POOL)

typedef float f4 __attribute__((ext_vector_type(4)));

__global__ __launch_bounds__(1024) void sort_items_kernel(
    const int* __restrict__ rois, int num_rois, int* __restrict__ perm)
{
    __shared__ int   base[64];
    __shared__ short s_y0[MAX_ITEMS];
    __shared__ int   s_yh[600];          // (y,h) per roi
    const int tid = threadIdx.x;
    const int num_items = num_rois * POOL;

    if (tid < 64) base[tid] = 0;
    for (int i = tid; i < num_rois; i += blockDim.x) {
        s_yh[i * 2]     = rois[i * 4 + 1];
        s_yh[i * 2 + 1] = rois[i * 4 + 3];
    }
    __syncthreads();

    // pass 1: y0 per item + histogram
    for (int i = tid; i < num_items; i += blockDim.x) {
        const int roi = i / POOL, py = i % POOL;
        const int y = s_yh[roi * 2], h = s_yh[roi * 2 + 1];
        const float fy = (float)y + (float)py * ((float)h * (1.0f / 14.0f));
        const int y0 = (int)floorf(fy) & 63;
        s_y0[i] = (short)y0;
        atomicAdd(&base[y0], 1);
    }
    __syncthreads();

    // wave-parallel exclusive scan over the 64 bins
    if (tid < 64) {
        const int orig = base[tid];
        int v = orig;
        #pragma unroll
        for (int d = 1; d < 64; d <<= 1) {
            const int t = __shfl_up(v, d, 64);
            if (tid >= d) v += t;
        }
        base[tid] = v - orig;
    }
    __syncthreads();

    // pass 2: scatter
    for (int i = tid; i < num_items; i += blockDim.x) {
        const int pos = atomicAdd(&base[(int)s_y0[i]], 1);
        perm[pos] = i;
    }
}

__global__ __launch_bounds__(256) void roi_pool_row_kernel(
    const float* __restrict__ fm,
    const int* __restrict__ rois,
    const int* __restrict__ perm,
    int nw,
    float* __restrict__ out)
{
    // bijective XCD swizzle (nw % 8 == 0): XCD j gets a contiguous y0 band
    const int per = nw >> 3;
    const int b   = blockIdx.x;
    const int sb  = (b & 7) * per + (b >> 3);
    const int item = perm[sb];

    const int py  = item % POOL;
    const int roi = item / POOL;

    const int4 r = *reinterpret_cast<const int4*>(rois + roi * 4);
    const int x = r.x, y = r.y, w = r.z, h = r.w;

    // Legacy-TF bilinear (align_corners=False, no half-pixel centers)
    const float fy = (float)y + (float)py * ((float)h * (1.0f / 14.0f));
    const int   y0 = (int)floorf(fy);
    const int   y1 = min(y0 + 1, y + h - 1);
    const float wy = fy - (float)y0;

    const int c = threadIdx.x;  // float4 lane over channels
    const f4* row0 = reinterpret_cast<const f4*>(fm) + (size_t)(y0 * FMW) * C4 + c;
    const f4* row1 = reinterpret_cast<const f4*>(fm) + (size_t)(y1 * FMW) * C4 + c;
    f4* op = reinterpret_cast<f4*>(out) + (size_t)((roi * POOL + py) * POOL) * C4 + c;

    const float wscale = (float)w * (1.0f / 14.0f);
    const int   xmax   = x + w - 1;

    // ---- software pipeline, 1 iteration deep ----
    // prologue: px = 0  (fx = x exactly -> x0 = x, wx = 0)
    {
    }
    const int x1p = min(x + 1, xmax);
    f4 a_tl = row0[(size_t)x * C4];
    f4 a_tr = row0[(size_t)x1p * C4];
    f4 a_bl = row1[(size_t)x * C4];
    f4 a_br = row1[(size_t)x1p * C4];
    float a_wx = 0.0f;

    #pragma unroll 1
    for (int px = 0; px < POOL - 1; ++px) {
        // issue NEXT px loads first -> this iteration's store is younger
        // than these loads and never gates the next compute's vmcnt wait
        const float fx  = (float)x + (float)(px + 1) * wscale;
        const int   x0  = (int)floorf(fx);
        const int   x1  = min(x0 + 1, xmax);
        const float nwx = fx - (float)x0;
        const f4 n_tl = row0[(size_t)x0 * C4];
        const f4 n_tr = row0[(size_t)x1 * C4];
        const f4 n_bl = row1[(size_t)x0 * C4];
        const f4 n_br = row1[(size_t)x1 * C4];

        const f4 top = a_tl + a_wx * (a_tr - a_tl);
        const f4 bot = a_bl + a_wx * (a_br - a_bl);
        const f4 o   = top + wy * (bot - top);
        __builtin_nontemporal_store(o, op + (size_t)px * C4);

        a_tl = n_tl; a_tr = n_tr; a_bl = n_bl; a_br = n_br; a_wx = nwx;
    }
    // epilogue: px = POOL-1
    {
        const f4 top = a_tl + a_wx * (a_tr - a_tl);
        const f4 bot = a_bl + a_wx * (a_br - a_bl);
        const f4 o   = top + wy * (bot - top);
        __builtin_nontemporal_store(o, op + (size_t)(POOL - 1) * C4);
    }
}

// Fallback without permutation (identity order), same pipelined loop.
__global__ __launch_bounds__(256) void roi_pool_row_kernel_noperm(
    const float* __restrict__ fm,
    const int* __restrict__ rois,
    int nw,
    float* __restrict__ out)
{
    const int sb  = blockIdx.x;
    const int py  = sb % POOL;
    const int roi = sb / POOL;

    const int4 r = *reinterpret_cast<const int4*>(rois + roi * 4);
    const int x = r.x, y = r.y, w = r.z, h = r.w;

    const float fy = (float)y + (float)py * ((float)h * (1.0f / 14.0f));
    const int   y0 = (int)floorf(fy);
    const int   y1 = min(y0 + 1, y + h - 1);
    const float wy = fy - (float)y0;

    const int c = threadIdx.x;
    const f4* row0 = reinterpret_cast<const f4*>(fm) + (size_t)(y0 * FMW) * C4 + c;
    const f4* row1 = reinterpret_cast<const f4*>(fm) + (size_t)(y1 * FMW) * C4 + c;
    f4* op = reinterpret_cast<f4*>(out) + (size_t)((roi * POOL + py) * POOL) * C4 + c;

    const float wscale = (float)w * (1.0f / 14.0f);
    const int   xmax   = x + w - 1;

    const int x1p = min(x + 1, xmax);
    f4 a_tl = row0[(size_t)x * C4];
    f4 a_tr = row0[(size_t)x1p * C4];
    f4 a_bl = row1[(size_t)x * C4];
    f4 a_br = row1[(size_t)x1p * C4];
    float a_wx = 0.0f;

    #pragma unroll 1
    for (int px = 0; px < POOL - 1; ++px) {
        const float fx  = (float)x + (float)(px + 1) * wscale;
        const int   x0  = (int)floorf(fx);
        const int   x1  = min(x0 + 1, xmax);
        const float nwx = fx - (float)x0;
        const f4 n_tl = row0[(size_t)x0 * C4];
        const f4 n_tr = row0[(size_t)x1 * C4];
        const f4 n_bl = row1[(size_t)x0 * C4];
        const f4 n_br = row1[(size_t)x1 * C4];

        const f4 top = a_tl + a_wx * (a_tr - a_tl);
        const f4 bot = a_bl + a_wx * (a_br - a_bl);
        const f4 o   = top + wy * (bot - top);
        __builtin_nontemporal_store(o, op + (size_t)px * C4);

        a_tl = n_tl; a_tr = n_tr; a_bl = n_bl; a_br = n_br; a_wx = nwx;
    }
    {
        const f4 top = a_tl + a_wx * (a_tr - a_tl);
        const f4 bot = a_bl + a_wx * (a_br - a_bl);
        const f4 o   = top + wy * (bot - top);
        __builtin_nontemporal_store(o, op + (size_t)(POOL - 1) * C4);
    }
}

extern "C" void kernel_launch(void* const* d_in, const int* in_sizes, int n_in,
                              void* d_out, int out_size, void* d_ws, size_t ws_size,
                              hipStream_t stream) {
    const float* fm  = (const float*)d_in[0];   // [1,64,64,1024] f32
    const int* rois  = (const int*)d_in[1];     // [1,300,4] i32
    float* out       = (float*)d_out;           // [1,300,14,14,1024] f32

    const int num_rois = in_sizes[1] / 4;       // 300
    const int nw = num_rois * POOL;             // 4200 work items

    if (ws_size >= (size_t)nw * sizeof(int) && (nw & 7) == 0 && nw <= MAX_ITEMS) {
        int* perm = (int*)d_ws;
        sort_items_kernel<<<1, 1024, 0, stream>>>(rois, num_rois, perm);
        roi_pool_row_kernel<<<nw, 256, 0, stream>>>(fm, rois, perm, nw, out);
    } else {
        roi_pool_row_kernel_noperm<<<nw, 256, 0, stream>>>(fm, rois, nw, out);
    }
}